// Round 7
// baseline (262.118 us; speedup 1.0000x reference)
//
#include <hip/hip_runtime.h>
#include <hip/hip_bf16.h>
#include <math.h>

#define B_ 64
#define L_ 512
#define D_ 768
#define H_ 384
#define T_ 9
#define M_ (B_ * L_)   // 32768 rows

typedef __attribute__((ext_vector_type(8))) short short8;
typedef __attribute__((ext_vector_type(4))) float f32x4;

__device__ __forceinline__ unsigned short f2bf(float f) {
    unsigned u = __float_as_uint(f);
    u += 0x7FFFu + ((u >> 16) & 1u);   // RNE
    return (unsigned short)(u >> 16);
}

__device__ __forceinline__ unsigned pkbf2(float a, float b) {
    __hip_bfloat162 h = __float22bfloat162_rn(float2{a, b});
    return *(unsigned*)&h;
}

// tanh-form gelu via sigmoid — 1 exp.
__device__ __forceinline__ float gelu_fast(float x) {
    float z2 = 1.5957691216f * x + 0.0713548162726f * x * x * x;
    return x / (1.f + __expf(-z2));
}

__device__ __forceinline__ float wredf(float v) {
#pragma unroll
    for (int m = 32; m >= 1; m >>= 1) v += __shfl_xor(v, m, 64);
    return v;
}

// -----------------------------------------------------------------------------
// Kernel 0: fragment-ordered bf16 weights + zero d_out.
//   W1F[((nt*24 + kc)*64 + lane)*8 + j] = W1[kc*32 + q*8 + j][nt*16 + lm]
//   W2F[(kk*64 + lane)*8 + j]           = (lm<9) ? W2[kk*32 + q*8 + j][lm] : 0
// -----------------------------------------------------------------------------
__global__ __launch_bounds__(256) void prep_kernel(
    const float* __restrict__ W1, const float* __restrict__ W2,
    unsigned short* __restrict__ W1F, unsigned short* __restrict__ W2F,
    float* __restrict__ out)
{
    if (blockIdx.x == 0 && threadIdx.x == 0) out[0] = 0.f;
    const int g    = blockIdx.x * 4 + (threadIdx.x >> 6);
    const int lane = threadIdx.x & 63;
    const int lm   = lane & 15;
    const int q    = lane >> 4;
    if (g < 576) {                       // W1F: g = nt*24 + kc
        const int nt = g / 24;
        const int kc = g - nt * 24;
        const int n  = nt * 16 + lm;
        short8 v;
#pragma unroll
        for (int j = 0; j < 8; ++j)
            v[j] = (short)f2bf(W1[(size_t)(kc * 32 + q * 8 + j) * H_ + n]);
        *(short8*)(W1F + ((size_t)g * 64 + lane) * 8) = v;
    } else if (g < 588) {                // W2F: kk = g - 576
        const int kk = g - 576;
        short8 v;
#pragma unroll
        for (int j = 0; j < 8; ++j) {
            int k = kk * 32 + q * 8 + j;
            v[j] = (lm < 9) ? (short)f2bf(W2[(size_t)k * T_ + lm]) : (short)0;
        }
        *(short8*)(W2F + ((size_t)kk * 64 + lane) * 8) = v;
    }
}

// -----------------------------------------------------------------------------
// Kernel 1: emissions = gelu(X @ W1 + b1) @ W2 + b2 — BARRIER-FREE K-loop.
// BM=64, BN=384, grid 512, 256 thr. Each lane loads its MFMA A-fragment
// DIRECTLY from row-major X (8 contiguous k per lane = two float4), converts
// in-register; B direct from fragment-ordered W1F (L2). No LDS, no
// __syncthreads in the K-loop — waves run free, compiler software-pipelines
// the fully-unrolled loop. LDS used only for the one-time W2 epilogue.
// Wave w: 4 m-tiles x 6 n-tiles (cols w*96..+95) = 24 MFMA/iter.
// -----------------------------------------------------------------------------
__global__ __launch_bounds__(256, 2) void emis_mfma_kernel(
    const float* __restrict__ X,             // [M_][768] fp32
    const unsigned short* __restrict__ W1F,  // fragment-ordered bf16
    const float* __restrict__ b1,
    const unsigned short* __restrict__ W2F,  // fragment-ordered bf16
    const float* __restrict__ b2,
    float* __restrict__ em)                  // [M_][9]
{
    __shared__ unsigned short Hs[64 * 392];  // 50176 B, epilogue only

    const int t    = threadIdx.x;
    const int lane = t & 63;
    const int w    = t >> 6;        // n-group: cols w*96..+95
    const int lm   = lane & 15;
    const int q    = lane >> 4;
    const int row0 = blockIdx.x * 64;

    // A fragment pointers: lane (lm,q) reads X[row0+mt*16+lm][kc*32+q*8 .. +8]
    const float* xa[4];
#pragma unroll
    for (int mt = 0; mt < 4; ++mt)
        xa[mt] = X + (size_t)(row0 + mt * 16 + lm) * D_ + (q << 3);

    // B fragment pointers, one per n-tile; advance 512 shorts per kc
    const unsigned short* bp[6];
#pragma unroll
    for (int i = 0; i < 6; ++i)
        bp[i] = W1F + ((size_t)(w * 6 + i) * 24 * 64 + lane) * 8;

    f32x4 acc[4][6];
#pragma unroll
    for (int mt = 0; mt < 4; ++mt)
#pragma unroll
        for (int i = 0; i < 6; ++i) acc[mt][i] = (f32x4)0.f;

#pragma unroll
    for (int kc = 0; kc < 24; ++kc) {
        short8 af[4];
#pragma unroll
        for (int mt = 0; mt < 4; ++mt) {
            float4 a0 = *(const float4*)(xa[mt] + kc * 32);
            float4 a1 = *(const float4*)(xa[mt] + kc * 32 + 4);
            int4 iv = {(int)pkbf2(a0.x, a0.y), (int)pkbf2(a0.z, a0.w),
                       (int)pkbf2(a1.x, a1.y), (int)pkbf2(a1.z, a1.w)};
            af[mt] = *(short8*)&iv;
        }
        short8 bf[6];
#pragma unroll
        for (int i = 0; i < 6; ++i)
            bf[i] = *(const short8*)(bp[i] + (size_t)kc * 512);
#pragma unroll
        for (int mt = 0; mt < 4; ++mt)
#pragma unroll
            for (int i = 0; i < 6; ++i)
                acc[mt][i] = __builtin_amdgcn_mfma_f32_16x16x32_bf16(
                    af[mt], bf[i], acc[mt][i], 0, 0, 0);
    }

    // ---- epilogue A: +b1, gelu -> Hs (bf16, 64 rows x 384 cols, stride 392) ----
#pragma unroll
    for (int i = 0; i < 6; ++i) {
        const int col = w * 96 + i * 16 + lm;
        const float b1v = b1[col];
#pragma unroll
        for (int mt = 0; mt < 4; ++mt)
#pragma unroll
            for (int r = 0; r < 4; ++r) {
                float h = gelu_fast(acc[mt][i][r] + b1v);
                Hs[(mt * 16 + q * 4 + r) * 392 + col] = f2bf(h);
            }
    }
    __syncthreads();

    // ---- epilogue B: em = h @ W2 via MFMA; wave w handles m-tile w ----
    f32x4 e = (f32x4)0.f;
#pragma unroll
    for (int kk = 0; kk < 12; ++kk) {
        short8 ah = *(const short8*)&Hs[(w * 16 + lm) * 392 + kk * 32 + (q << 3)];
        short8 bw = *(const short8*)(W2F + ((size_t)(kk * 64 + lane)) * 8);
        e = __builtin_amdgcn_mfma_f32_16x16x32_bf16(ah, bw, e, 0, 0, 0);
    }
    if (lm < 9) {
        const float b2v = b2[lm];
#pragma unroll
        for (int r = 0; r < 4; ++r)
            em[(size_t)(row0 + w * 16 + q * 4 + r) * T_ + lm] = e[r] + b2v;
    }
}

// -----------------------------------------------------------------------------
// Kernel 2: CRF — unchanged (R6). 64 blocks x 576 threads; Phase A chunk
// transfer matrices (trans in registers), wave 0 serial combine + wave 1
// numerator; atomicAdd into d_out (zeroed by prep).
// -----------------------------------------------------------------------------
__global__ __launch_bounds__(576) void crf_kernel(
    const float* __restrict__ em,
    const int* __restrict__ labels,
    const unsigned char* __restrict__ maskb,
    const float* __restrict__ st,
    const float* __restrict__ et,
    const float* __restrict__ tr,
    float* __restrict__ out)
{
    const int b = blockIdx.x;
    const int t = threadIdx.x;

    __shared__ float es[64 * 73];     // es[c*73 + s*9 + j]
    __shared__ float Ms[64 * 81];
    __shared__ float trs[81];
    __shared__ float red[2];
    __shared__ unsigned char msh[L_];
    __shared__ int lbs[L_];

    const int mstride =
        (maskb[0] != 0 && maskb[1] == 0 && maskb[2] == 0 && maskb[3] == 0) ? 4 : 1;

    const float* eb = em + (size_t)b * L_ * T_;
    for (int i = t; i < L_ * T_; i += 576) {
        int tt = i / T_, j = i - tt * T_;
        es[(tt >> 3) * 73 + (tt & 7) * 9 + j] = eb[i];
    }
    if (t < 81) trs[t] = tr[t];
    for (int i = t; i < L_; i += 576) {
        msh[i] = maskb[((size_t)b * L_ + i) * (size_t)mstride];
        lbs[i] = labels[b * L_ + i];
    }
    __syncthreads();

    // ---- Phase A ----
    {
        const int c  = t / 9;
        const int i0 = t - c * 9;
        float trr[81];
#pragma unroll
        for (int i = 0; i < 81; ++i) trr[i] = trs[i];
        float V[9];
#pragma unroll
        for (int j = 0; j < 9; ++j) V[j] = (j == i0) ? 0.f : -1e30f;

        const int sbeg = (c == 0) ? 1 : 0;
        for (int s = sbeg; s < 8; ++s) {
            int tt = c * 8 + s;
            if (msh[tt]) {
                const float* ep = &es[c * 73 + s * 9];
                float nv[9];
#pragma unroll
                for (int j = 0; j < 9; ++j) {
                    float a[9];
#pragma unroll
                    for (int k = 0; k < 9; ++k) a[k] = V[k] + trr[k * 9 + j];
                    float mx = a[0];
#pragma unroll
                    for (int k = 1; k < 9; ++k) mx = fmaxf(mx, a[k]);
                    float sum = 0.f;
#pragma unroll
                    for (int k = 0; k < 9; ++k) sum += __expf(a[k] - mx);
                    nv[j] = ep[j] + mx + __logf(sum);
                }
#pragma unroll
                for (int j = 0; j < 9; ++j) V[j] = nv[j];
            }
        }
#pragma unroll
        for (int j = 0; j < 9; ++j) Ms[c * 81 + i0 * 9 + j] = V[j];
    }
    __syncthreads();

    const int lane = t & 63;
    const int w    = t >> 6;
    if (w == 0) {
        // ---- Phase B: serial combine of 64 chunk matrices ----
        const int jj = lane < 9 ? lane : 8;
        float alpha = (lane < 9) ? st[jj] + es[jj] : -1e30f;
        for (int c = 0; c < 64; ++c) {
            float a[9];
#pragma unroll
            for (int i = 0; i < 9; ++i) {
                float av = __shfl(alpha, i, 64);
                a[i] = av + Ms[c * 81 + i * 9 + jj];
            }
            float mx = a[0];
#pragma unroll
            for (int i = 1; i < 9; ++i) mx = fmaxf(mx, a[i]);
            float sum = 0.f;
#pragma unroll
            for (int i = 0; i < 9; ++i) sum += __expf(a[i] - mx);
            float nv = mx + __logf(sum);
            if (lane < 9) alpha = nv;
        }
        float v = (lane < 9) ? alpha + et[jj] : -1e30f;
        float mx = v;
#pragma unroll
        for (int m = 32; m >= 1; m >>= 1) mx = fmaxf(mx, __shfl_xor(mx, m, 64));
        float s = __expf(v - mx);
        s = wredf(s);
        if (lane == 0) red[0] = mx + __logf(s);   // denom
    } else if (w == 1) {
        // ---- numerator ----
        float emit_s = 0.f, tr_sc = 0.f, mcnt = 0.f;
        for (int tt = lane; tt < L_; tt += 64) {
            if (msh[tt]) {
                mcnt += 1.f;
                int tag = lbs[tt];
                emit_s += es[(tt >> 3) * 73 + (tt & 7) * 9 + tag];
                if (tt >= 1) tr_sc += trs[lbs[tt - 1] * 9 + tag];
            }
        }
        emit_s = wredf(emit_s);
        tr_sc  = wredf(tr_sc);
        mcnt   = wredf(mcnt);
        if (lane == 0) {
            int last = (int)mcnt - 1;
            red[1] = st[lbs[0]] + emit_s + tr_sc + et[lbs[last]];
        }
    }
    __syncthreads();
    if (t == 0) atomicAdd(out, (red[0] - red[1]) * (1.0f / (float)B_));
}

extern "C" void kernel_launch(void* const* d_in, const int* in_sizes, int n_in,
                              void* d_out, int out_size, void* d_ws, size_t ws_size,
                              hipStream_t stream) {
    const float*         enc    = (const float*)d_in[0];
    const int*           labels = (const int*)d_in[1];
    const unsigned char* mask   = (const unsigned char*)d_in[2];
    const float*         W1     = (const float*)d_in[3];
    const float*         b1     = (const float*)d_in[4];
    const float*         W2     = (const float*)d_in[5];
    const float*         b2     = (const float*)d_in[6];
    const float*         st     = (const float*)d_in[7];
    const float*         et     = (const float*)d_in[8];
    const float*         tr     = (const float*)d_in[9];

    float* em           = (float*)d_ws;                               // 1,179,648 B
    unsigned short* W1F = (unsigned short*)(em + (size_t)M_ * T_);    // 589,824 B
    unsigned short* W2F = W1F + (size_t)576 * 64 * 8;                 // 12,288 B

    prep_kernel<<<147, 256, 0, stream>>>(W1, W2, W1F, W2F, (float*)d_out);
    emis_mfma_kernel<<<M_ / 64, 256, 0, stream>>>(enc, W1F, b1, W2F, b2, em);
    crf_kernel<<<B_, 576, 0, stream>>>(em, labels, mask, st, et, tr, (float*)d_out);
}

// Round 8
// 233.187 us; speedup vs baseline: 1.1241x; 1.1241x over previous
//
#include <hip/hip_runtime.h>
#include <hip/hip_bf16.h>
#include <math.h>

#define B_ 64
#define L_ 512
#define D_ 768
#define H_ 384
#define T_ 9
#define M_ (B_ * L_)   // 32768 rows

typedef __attribute__((ext_vector_type(8))) short short8;
typedef __attribute__((ext_vector_type(4))) float f32x4;

__device__ __forceinline__ unsigned short f2bf(float f) {
    unsigned u = __float_as_uint(f);
    u += 0x7FFFu + ((u >> 16) & 1u);   // RNE
    return (unsigned short)(u >> 16);
}

__device__ __forceinline__ unsigned pkbf2(float a, float b) {
    __hip_bfloat162 h = __float22bfloat162_rn(float2{a, b});
    return *(unsigned*)&h;
}

// tanh-form gelu via sigmoid — 1 exp.
__device__ __forceinline__ float gelu_fast(float x) {
    float z2 = 1.5957691216f * x + 0.0713548162726f * x * x * x;
    return x / (1.f + __expf(-z2));
}

__device__ __forceinline__ float wredf(float v) {
#pragma unroll
    for (int m = 32; m >= 1; m >>= 1) v += __shfl_xor(v, m, 64);
    return v;
}

// LDS-only barrier: global loads stay in flight across it.
__device__ __forceinline__ void sync_lds() {
    asm volatile("s_waitcnt lgkmcnt(0)\n\ts_barrier" ::: "memory");
}

// -----------------------------------------------------------------------------
// Kernel 0: fragment-ordered bf16 weights + zero d_out.
//   W1F[((nt*24 + kc)*64 + lane)*8 + j] = W1[kc*32 + q*8 + j][nt*16 + lm]
//   W2F[(kk*64 + lane)*8 + j]           = (lm<9) ? W2[kk*32 + q*8 + j][lm] : 0
// -----------------------------------------------------------------------------
__global__ __launch_bounds__(256) void prep_kernel(
    const float* __restrict__ W1, const float* __restrict__ W2,
    unsigned short* __restrict__ W1F, unsigned short* __restrict__ W2F,
    float* __restrict__ out)
{
    if (blockIdx.x == 0 && threadIdx.x == 0) out[0] = 0.f;
    const int g    = blockIdx.x * 4 + (threadIdx.x >> 6);
    const int lane = threadIdx.x & 63;
    const int lm   = lane & 15;
    const int q    = lane >> 4;
    if (g < 576) {                       // W1F: g = nt*24 + kc
        const int nt = g / 24;
        const int kc = g - nt * 24;
        const int n  = nt * 16 + lm;
        short8 v;
#pragma unroll
        for (int j = 0; j < 8; ++j)
            v[j] = (short)f2bf(W1[(size_t)(kc * 32 + q * 8 + j) * H_ + n]);
        *(short8*)(W1F + ((size_t)g * 64 + lane) * 8) = v;
    } else if (g < 588) {                // W2F: kk = g - 576
        const int kk = g - 576;
        short8 v;
#pragma unroll
        for (int j = 0; j < 8; ++j) {
            int k = kk * 32 + q * 8 + j;
            v[j] = (lm < 9) ? (short)f2bf(W2[(size_t)k * T_ + lm]) : (short)0;
        }
        *(short8*)(W2F + ((size_t)kk * 64 + lane) * 8) = v;
    }
}

// -----------------------------------------------------------------------------
// Kernel 1: emissions = gelu(X @ W1 + b1) @ W2 + b2.
// BM=64, BN=384, BK=96: 8 barrier'd stages (vs 24), each staging 3 k-chunks.
// Depth-2 X register prefetch issued a FULL STAGE early (~1000 cyc slack >
// HBM ~900) across the LDS-only barrier. Wave w: 4 mt x 6 nt x 3 kc = 72
// MFMA/stage; B at-use from fragment-ordered W1F (L2). 256 thr, grid 512.
// -----------------------------------------------------------------------------
__global__ __launch_bounds__(256, 2) void emis_mfma_kernel(
    const float* __restrict__ X,             // [M_][768] fp32
    const unsigned short* __restrict__ W1F,  // fragment-ordered bf16
    const float* __restrict__ b1,
    const unsigned short* __restrict__ W2F,  // fragment-ordered bf16
    const float* __restrict__ b2,
    float* __restrict__ em)                  // [M_][9]
{
    __shared__ unsigned short Sh[64 * 392];  // 50176 B (epilogue Hs)
    // As[s][c] at ((s*3+c)*64*40) shorts; 2*3*64*40 = 15360 shorts (30,720 B)
    unsigned short* As = Sh;

    const int t    = threadIdx.x;
    const int lane = t & 63;
    const int w    = t >> 6;        // n-group: cols w*96..+95
    const int lm   = lane & 15;
    const int q    = lane >> 4;
    const int row0 = blockIdx.x * 64;

    const int ar  = t >> 2;         // staging row 0..63
    const int ako = (t & 3) << 3;   // staging k-offset 0,8,16,24
    const float* xp = X + (size_t)(row0 + ar) * D_ + ako;

    f32x4 acc[4][6];
#pragma unroll
    for (int mt = 0; mt < 4; ++mt)
#pragma unroll
        for (int i = 0; i < 6; ++i) acc[mt][i] = (f32x4)0.f;

    // ---- prologue: stage 0 -> As[0] directly; stages 1,2 into registers ----
#pragma unroll
    for (int c = 0; c < 3; ++c) {
        float4 p0 = *(const float4*)(xp + c * 32);
        float4 p1 = *(const float4*)(xp + c * 32 + 4);
        int4 v = {(int)pkbf2(p0.x, p0.y), (int)pkbf2(p0.z, p0.w),
                  (int)pkbf2(p1.x, p1.y), (int)pkbf2(p1.z, p1.w)};
        *(int4*)&As[(size_t)(c * 64 + ar) * 40 + ako] = v;
    }
    float4 xv[2][3][2];   // xv[p][c]: stage (st+1) at iter st in slot p=st&1... see loop
#pragma unroll
    for (int c = 0; c < 3; ++c) {
        xv[0][c][0] = *(const float4*)(xp + (3 + c) * 32);       // stage 1
        xv[0][c][1] = *(const float4*)(xp + (3 + c) * 32 + 4);
        xv[1][c][0] = *(const float4*)(xp + (6 + c) * 32);       // stage 2
        xv[1][c][1] = *(const float4*)(xp + (6 + c) * 32 + 4);
    }

#pragma unroll
    for (int st = 0; st < 8; ++st) {
        const int s = st & 1;
        sync_lds();                        // As[s] visible; vmcnt NOT drained
#pragma unroll
        for (int c = 0; c < 3; ++c) {
            short8 af[4];
#pragma unroll
            for (int mt = 0; mt < 4; ++mt)
                af[mt] = *(const short8*)&As[(size_t)((s * 3 + c) * 64 + mt * 16 + lm) * 40 + (q << 3)];
#pragma unroll
            for (int i = 0; i < 6; ++i) {
                short8 bf = *(const short8*)(W1F +
                    (((size_t)(w * 6 + i) * 24 + st * 3 + c) * 64 + lane) * 8);
#pragma unroll
                for (int mt = 0; mt < 4; ++mt)
                    acc[mt][i] = __builtin_amdgcn_mfma_f32_16x16x32_bf16(
                        af[mt], bf, acc[mt][i], 0, 0, 0);
            }
        }
        if (st < 7) {
            // convert stage st+1 (held in xv[s]) -> As[s^1]
#pragma unroll
            for (int c = 0; c < 3; ++c) {
                float4 x0 = xv[s][c][0], x1 = xv[s][c][1];
                int4 v = {(int)pkbf2(x0.x, x0.y), (int)pkbf2(x0.z, x0.w),
                          (int)pkbf2(x1.x, x1.y), (int)pkbf2(x1.z, x1.w)};
                *(int4*)&As[(size_t)(((s ^ 1) * 3 + c) * 64 + ar) * 40 + ako] = v;
            }
            // refill xv[s] with stage st+2 (in flight for a full stage)
            if (st < 6) {
#pragma unroll
                for (int c = 0; c < 3; ++c) {
                    xv[s][c][0] = *(const float4*)(xp + ((st + 2) * 3 + c) * 32);
                    xv[s][c][1] = *(const float4*)(xp + ((st + 2) * 3 + c) * 32 + 4);
                }
            }
        }
    }
    __syncthreads();   // full drain; safe to reuse Sh as Hs

    // ---- epilogue A: +b1, gelu -> Hs (bf16, 64 rows x 384 cols, stride 392) ----
#pragma unroll
    for (int i = 0; i < 6; ++i) {
        const int col = w * 96 + i * 16 + lm;
        const float b1v = b1[col];
#pragma unroll
        for (int mt = 0; mt < 4; ++mt)
#pragma unroll
            for (int r = 0; r < 4; ++r) {
                float h = gelu_fast(acc[mt][i][r] + b1v);
                Sh[(mt * 16 + q * 4 + r) * 392 + col] = f2bf(h);
            }
    }
    __syncthreads();

    // ---- epilogue B: em = h @ W2 via MFMA; wave w handles m-tile w ----
    f32x4 e = (f32x4)0.f;
#pragma unroll
    for (int kk = 0; kk < 12; ++kk) {
        short8 ah = *(const short8*)&Sh[(w * 16 + lm) * 392 + kk * 32 + (q << 3)];
        short8 bw = *(const short8*)(W2F + ((size_t)(kk * 64 + lane)) * 8);
        e = __builtin_amdgcn_mfma_f32_16x16x32_bf16(ah, bw, e, 0, 0, 0);
    }
    if (lm < 9) {
        const float b2v = b2[lm];
#pragma unroll
        for (int r = 0; r < 4; ++r)
            em[(size_t)(row0 + w * 16 + q * 4 + r) * T_ + lm] = e[r] + b2v;
    }
}

// -----------------------------------------------------------------------------
// Kernel 2: CRF — R6 configuration (best measured). 64 blocks x 576 threads.
// -----------------------------------------------------------------------------
__global__ __launch_bounds__(576) void crf_kernel(
    const float* __restrict__ em,
    const int* __restrict__ labels,
    const unsigned char* __restrict__ maskb,
    const float* __restrict__ st,
    const float* __restrict__ et,
    const float* __restrict__ tr,
    float* __restrict__ out)
{
    const int b = blockIdx.x;
    const int t = threadIdx.x;

    __shared__ float es[64 * 73];     // es[c*73 + s*9 + j]
    __shared__ float Ms[64 * 81];
    __shared__ float trs[81];
    __shared__ float red[2];
    __shared__ unsigned char msh[L_];
    __shared__ int lbs[L_];

    const int mstride =
        (maskb[0] != 0 && maskb[1] == 0 && maskb[2] == 0 && maskb[3] == 0) ? 4 : 1;

    const float* eb = em + (size_t)b * L_ * T_;
    for (int i = t; i < L_ * T_; i += 576) {
        int tt = i / T_, j = i - tt * T_;
        es[(tt >> 3) * 73 + (tt & 7) * 9 + j] = eb[i];
    }
    if (t < 81) trs[t] = tr[t];
    for (int i = t; i < L_; i += 576) {
        msh[i] = maskb[((size_t)b * L_ + i) * (size_t)mstride];
        lbs[i] = labels[b * L_ + i];
    }
    __syncthreads();

    // ---- Phase A ----
    {
        const int c  = t / 9;
        const int i0 = t - c * 9;
        float trr[81];
#pragma unroll
        for (int i = 0; i < 81; ++i) trr[i] = trs[i];
        float V[9];
#pragma unroll
        for (int j = 0; j < 9; ++j) V[j] = (j == i0) ? 0.f : -1e30f;

        const int sbeg = (c == 0) ? 1 : 0;
        for (int s = sbeg; s < 8; ++s) {
            int tt = c * 8 + s;
            if (msh[tt]) {
                const float* ep = &es[c * 73 + s * 9];
                float nv[9];
#pragma unroll
                for (int j = 0; j < 9; ++j) {
                    float a[9];
#pragma unroll
                    for (int k = 0; k < 9; ++k) a[k] = V[k] + trr[k * 9 + j];
                    float mx = a[0];
#pragma unroll
                    for (int k = 1; k < 9; ++k) mx = fmaxf(mx, a[k]);
                    float sum = 0.f;
#pragma unroll
                    for (int k = 0; k < 9; ++k) sum += __expf(a[k] - mx);
                    nv[j] = ep[j] + mx + __logf(sum);
                }
#pragma unroll
                for (int j = 0; j < 9; ++j) V[j] = nv[j];
            }
        }
#pragma unroll
        for (int j = 0; j < 9; ++j) Ms[c * 81 + i0 * 9 + j] = V[j];
    }
    __syncthreads();

    const int lane = t & 63;
    const int w    = t >> 6;
    if (w == 0) {
        // ---- Phase B: serial combine of 64 chunk matrices ----
        const int jj = lane < 9 ? lane : 8;
        float alpha = (lane < 9) ? st[jj] + es[jj] : -1e30f;
        for (int c = 0; c < 64; ++c) {
            float a[9];
#pragma unroll
            for (int i = 0; i < 9; ++i) {
                float av = __shfl(alpha, i, 64);
                a[i] = av + Ms[c * 81 + i * 9 + jj];
            }
            float mx = a[0];
#pragma unroll
            for (int i = 1; i < 9; ++i) mx = fmaxf(mx, a[i]);
            float sum = 0.f;
#pragma unroll
            for (int i = 0; i < 9; ++i) sum += __expf(a[i] - mx);
            float nv = mx + __logf(sum);
            if (lane < 9) alpha = nv;
        }
        float v = (lane < 9) ? alpha + et[jj] : -1e30f;
        float mx = v;
#pragma unroll
        for (int m = 32; m >= 1; m >>= 1) mx = fmaxf(mx, __shfl_xor(mx, m, 64));
        float s = __expf(v - mx);
        s = wredf(s);
        if (lane == 0) red[0] = mx + __logf(s);   // denom
    } else if (w == 1) {
        // ---- numerator ----
        float emit_s = 0.f, tr_sc = 0.f, mcnt = 0.f;
        for (int tt = lane; tt < L_; tt += 64) {
            if (msh[tt]) {
                mcnt += 1.f;
                int tag = lbs[tt];
                emit_s += es[(tt >> 3) * 73 + (tt & 7) * 9 + tag];
                if (tt >= 1) tr_sc += trs[lbs[tt - 1] * 9 + tag];
            }
        }
        emit_s = wredf(emit_s);
        tr_sc  = wredf(tr_sc);
        mcnt   = wredf(mcnt);
        if (lane == 0) {
            int last = (int)mcnt - 1;
            red[1] = st[lbs[0]] + emit_s + tr_sc + et[lbs[last]];
        }
    }
    __syncthreads();
    if (t == 0) atomicAdd(out, (red[0] - red[1]) * (1.0f / (float)B_));
}

extern "C" void kernel_launch(void* const* d_in, const int* in_sizes, int n_in,
                              void* d_out, int out_size, void* d_ws, size_t ws_size,
                              hipStream_t stream) {
    const float*         enc    = (const float*)d_in[0];
    const int*           labels = (const int*)d_in[1];
    const unsigned char* mask   = (const unsigned char*)d_in[2];
    const float*         W1     = (const float*)d_in[3];
    const float*         b1     = (const float*)d_in[4];
    const float*         W2     = (const float*)d_in[5];
    const float*         b2     = (const float*)d_in[6];
    const float*         st     = (const float*)d_in[7];
    const float*         et     = (const float*)d_in[8];
    const float*         tr     = (const float*)d_in[9];

    float* em           = (float*)d_ws;                               // 1,179,648 B
    unsigned short* W1F = (unsigned short*)(em + (size_t)M_ * T_);    // 589,824 B
    unsigned short* W2F = W1F + (size_t)576 * 64 * 8;                 // 12,288 B

    prep_kernel<<<147, 256, 0, stream>>>(W1, W2, W1F, W2F, (float*)d_out);
    emis_mfma_kernel<<<M_ / 64, 256, 0, stream>>>(enc, W1F, b1, W2F, b2, em);
    crf_kernel<<<B_, 576, 0, stream>>>(em, labels, mask, st, et, tr, (float*)d_out);
}